// Round 1
// baseline (150.363 us; speedup 1.0000x reference)
//
#include <hip/hip_runtime.h>
#include <math.h>

#define NPT 512   // N points per row
#define BROWS 4096

__global__ __launch_bounds__(NPT) void waypoint_smoother_kernel(
    const float* __restrict__ wp,    // (B, N, 2)
    const float* __restrict__ sww,   // scalar smooth_weight
    const float* __restrict__ W1,    // (4, 64)
    const float* __restrict__ b1,    // (64,)
    const float* __restrict__ W2,    // (64, 32)
    const float* __restrict__ b2,    // (32,)
    const float* __restrict__ W3,    // (32, 1)
    const float* __restrict__ b3,    // (1,)
    float* __restrict__ out)         // (B, N, 2)
{
    __shared__ float2 sWp[NPT];
    __shared__ float sA[NPT];
    __shared__ float sCx[NPT];
    __shared__ float sCy[NPT];

    const int b = blockIdx.x;
    const int i = threadIdx.x;

    const float2* wrow = (const float2*)(wp + (size_t)b * NPT * 2);
    float2 p = wrow[i];
    sWp[i] = p;
    __syncthreads();

    // ---- features: d1 (duplicated last), d2 (zero-padded ends) ----
    float2 pm = sWp[(i > 0) ? (i - 1) : 0];
    float2 pp = sWp[(i < NPT - 1) ? (i + 1) : (NPT - 1)];

    float d1x, d1y;
    if (i < NPT - 1) { d1x = pp.x - p.x; d1y = pp.y - p.y; }
    else             { d1x = p.x - pm.x; d1y = p.y - pm.y; }   // duplicate d1[N-2]

    float d2x = 0.f, d2y = 0.f;
    if (i >= 1 && i <= NPT - 2) {
        d2x = pp.x - 2.f * p.x + pm.x;
        d2y = pp.y - 2.f * p.y + pm.y;
    }

    // ---- MLP: 4 -> 64 -> 32 -> 1, relu/relu/sigmoid ----
    float h2[32];
    #pragma unroll
    for (int j = 0; j < 32; ++j) h2[j] = b2[j];

    #pragma unroll
    for (int k = 0; k < 64; ++k) {
        float h1k = b1[k];
        h1k = fmaf(d1x, W1[0 * 64 + k], h1k);
        h1k = fmaf(d1y, W1[1 * 64 + k], h1k);
        h1k = fmaf(d2x, W1[2 * 64 + k], h1k);
        h1k = fmaf(d2y, W1[3 * 64 + k], h1k);
        h1k = fmaxf(h1k, 0.f);
        #pragma unroll
        for (int j = 0; j < 32; ++j) {
            h2[j] = fmaf(h1k, W2[k * 32 + j], h2[j]);
        }
    }

    float acc = b3[0];
    #pragma unroll
    for (int j = 0; j < 32; ++j) acc = fmaf(fmaxf(h2[j], 0.f), W3[j], acc);

    float cw  = 1.f / (1.f + expf(-acc));
    float swv = 1.f / (1.f + expf(-sww[0]));
    float w   = swv * (1.f - cw);

    // ---- affine-scan recurrence: y_i = a_i*y_{i-1} + c_i ----
    // f_0 is the constant x_0 (a_0 = 0), so inclusive scan yields y_i = C_i.
    float a, cx, cy;
    if (i == 0) { a = 0.f; cx = p.x; cy = p.y; }
    else        { a = w;   cx = (1.f - w) * p.x; cy = (1.f - w) * p.y; }
    sA[i] = a; sCx[i] = cx; sCy[i] = cy;
    __syncthreads();

    #pragma unroll
    for (int off = 1; off < NPT; off <<= 1) {
        float a1 = 0.f, cx1 = 0.f, cy1 = 0.f;
        const bool has = (i >= off);
        if (has) { a1 = sA[i - off]; cx1 = sCx[i - off]; cy1 = sCy[i - off]; }
        __syncthreads();
        if (has) {
            // compose: current f after partner prefix g: (a*a1, a*c1 + c)
            cx = fmaf(a, cx1, cx);
            cy = fmaf(a, cy1, cy);
            a  = a * a1;
            sA[i] = a; sCx[i] = cx; sCy[i] = cy;
        }
        __syncthreads();
    }

    // ---- write output, endpoint pinned to original ----
    float2 o;
    if (i == NPT - 1) { o = p; }
    else              { o.x = cx; o.y = cy; }
    ((float2*)(out + (size_t)b * NPT * 2))[i] = o;
}

extern "C" void kernel_launch(void* const* d_in, const int* in_sizes, int n_in,
                              void* d_out, int out_size, void* d_ws, size_t ws_size,
                              hipStream_t stream) {
    const float* wp  = (const float*)d_in[0];
    const float* sww = (const float*)d_in[1];
    const float* W1  = (const float*)d_in[2];
    const float* b1  = (const float*)d_in[3];
    const float* W2  = (const float*)d_in[4];
    const float* b2  = (const float*)d_in[5];
    const float* W3  = (const float*)d_in[6];
    const float* b3  = (const float*)d_in[7];
    float* out = (float*)d_out;

    waypoint_smoother_kernel<<<BROWS, NPT, 0, stream>>>(
        wp, sww, W1, b1, W2, b2, W3, b3, out);
}